// Round 7
// baseline (153.521 us; speedup 1.0000x reference)
//
#include <hip/hip_runtime.h>
#include <hip/hip_bf16.h>

// Problem constants
constexpr int Bn  = 8;
constexpr int Cn  = 1024;
constexpr int Tn  = 4096;
constexpr int Hn  = 16;
constexpr int Kn  = 15;
constexpr int Fp  = 256;   // padded f dim: row = h*16 + k, k==15 is zero pad

typedef __attribute__((ext_vector_type(8))) short    bf16x8;
typedef __attribute__((ext_vector_type(4))) float    f32x4;

static __device__ __forceinline__ unsigned short f2bf(float f) {
    __hip_bfloat16 h = __float2bfloat16(f);   // round-to-nearest-even
    return *reinterpret_cast<unsigned short*>(&h);
}

// ---------------------------------------------------------------------------
// P1: build padded bf16 W' (256 x 1024) from W (240 x 1024) f32.
// ---------------------------------------------------------------------------
__global__ __launch_bounds__(256)
void lwc_wpad(const float* __restrict__ W, unsigned short* __restrict__ Wp)
{
    const int idx = (blockIdx.x * 256 + threadIdx.x) * 4;  // over 256*1024
    const int m = idx >> 10, c = idx & 1023;
    const int h = m >> 4, k = m & 15;
    float4 v = make_float4(0.f, 0.f, 0.f, 0.f);
    if (k < 15)
        v = *reinterpret_cast<const float4*>(W + ((size_t)(h * 15 + k)) * Cn + c);
    ushort4 o;
    o.x = f2bf(v.x); o.y = f2bf(v.y); o.z = f2bf(v.z); o.w = f2bf(v.w);
    *reinterpret_cast<ushort4*>(Wp + idx) = o;
}

// ---------------------------------------------------------------------------
// Fused transpose + GEMM + softmax (round-4 verified version, unchanged).
// grid (Tn/64, Bn), block 256 (4 waves). w (B,H,K,T) f32 -> d_ws.
// ---------------------------------------------------------------------------
__global__ __launch_bounds__(256)
void lwc_fused_weights(const float* __restrict__ x,
                       const unsigned short* __restrict__ Wp,
                       float* __restrict__ wout)
{
    __shared__ __align__(16) unsigned short xs[2 * 16 * 64 * 8];   // 32 KiB

    const int tid  = threadIdx.x;
    const int lane = tid & 63;
    const int wv   = tid >> 6;
    const int t0   = blockIdx.x * 64;
    const int b    = blockIdx.y;

    const int lr = lane & 15;
    const int lg = lane >> 4;

    const int tcell = tid & 15;
    const int coct  = tid >> 4;
    const float* xbase = x + (size_t)b * Cn * Tn + t0 + tcell * 4;

    f32x4 acc[4][4];
#pragma unroll
    for (int i = 0; i < 4; ++i)
#pragma unroll
        for (int j = 0; j < 4; ++j) acc[i][j] = (f32x4){0.f, 0.f, 0.f, 0.f};

    float4 ld[8];
#pragma unroll
    for (int j = 0; j < 8; ++j)
        ld[j] = *reinterpret_cast<const float4*>(
            xbase + (size_t)(coct * 8 + j) * Tn);

    const unsigned short* Abase = Wp + ((size_t)(wv * 64 + lr)) * Cn + lg * 8;
    const int lrx0 = lr ^ lg;
    unsigned short* wrow = xs + coct * 512;
    const int csw = coct & 7;

#pragma unroll 1
    for (int ck = 0; ck < 8; ++ck) {
        const int buf = (ck & 1) * 8192;

        float cf[8][4];
#pragma unroll
        for (int j = 0; j < 8; ++j) {
            cf[j][0] = ld[j].x; cf[j][1] = ld[j].y;
            cf[j][2] = ld[j].z; cf[j][3] = ld[j].w;
        }
#pragma unroll
        for (int tt = 0; tt < 4; ++tt) {
            const int slotw = (tcell * 4 + tt) ^ csw;
            bf16x8 pk;
#pragma unroll
            for (int j = 0; j < 8; ++j) pk[j] = (short)f2bf(cf[j][tt]);
            *reinterpret_cast<bf16x8*>(wrow + buf + slotw * 8) = pk;
        }

        __syncthreads();

        if (ck < 7) {
#pragma unroll
            for (int j = 0; j < 8; ++j)
                ld[j] = *reinterpret_cast<const float4*>(
                    xbase + (size_t)((ck + 1) * 128 + coct * 8 + j) * Tn);
        }

        const unsigned short* Apc = Abase + ck * 128;
#pragma unroll
        for (int ks = 0; ks < 4; ++ks) {
            bf16x8 af[4], bfr[4];
            const unsigned short* ap = Apc + ks * 32;
#pragma unroll
            for (int mi = 0; mi < 4; ++mi)
                af[mi] = *reinterpret_cast<const bf16x8*>(ap + (size_t)mi * 16 * Cn);
            const int lrx = lrx0 ^ ((ks & 1) << 2);
            const unsigned short* bp = xs + buf + (ks * 4 + lg) * 512 + lrx * 8;
#pragma unroll
            for (int ni = 0; ni < 4; ++ni)
                bfr[ni] = *reinterpret_cast<const bf16x8*>(bp + ni * 128);
#pragma unroll
            for (int mi = 0; mi < 4; ++mi)
#pragma unroll
                for (int ni = 0; ni < 4; ++ni)
                    acc[mi][ni] = __builtin_amdgcn_mfma_f32_16x16x32_bf16(
                        af[mi], bfr[ni], acc[mi][ni], 0, 0, 0);
        }
    }

    const int tcol = lane & 15;
#pragma unroll
    for (int mi = 0; mi < 4; ++mi) {
        const int h = wv * 4 + mi;
        float* hbase = wout + (((size_t)b * Hn + h) * Kn) * Tn + t0;
#pragma unroll
        for (int ni = 0; ni < 4; ++ni) {
            f32x4 v = acc[mi][ni];
            float mx = -3.0e38f;
#pragma unroll
            for (int r = 0; r < 4; ++r)
                if (lg * 4 + r < 15) mx = fmaxf(mx, v[r]);
            mx = fmaxf(mx, __shfl_xor(mx, 16));
            mx = fmaxf(mx, __shfl_xor(mx, 32));
            float e[4], s = 0.f;
#pragma unroll
            for (int r = 0; r < 4; ++r) {
                const int k = lg * 4 + r;
                e[r] = (k < 15) ? __expf(v[r] - mx) : 0.f;
                s += e[r];
            }
            s += __shfl_xor(s, 16);
            s += __shfl_xor(s, 32);
            const float inv = 1.f / s;
#pragma unroll
            for (int r = 0; r < 4; ++r) {
                const int k = lg * 4 + r;
                if (k < 15)
                    hbase[(size_t)k * Tn + ni * 16 + tcol] = e[r] * inv;
            }
        }
    }
}

// ---------------------------------------------------------------------------
// Kernel B (max parallelism): one thread = one (channel, 4-t quad).
// No serial channel loop, no LDS. grid (Tn/64, H*4, Bn) = 32768 blocks.
// thread: tq = tid&15 (t-quad in 64-t tile), rl = tid>>4 (channel row in
// 16-row quarter). Wave = 4 rows x 16 quads: x coalesced per row, w taps
// broadcast across the 4 row-lanes. Nontemporal store (via ext-vector f32x4;
// HIP float4* is rejected by the builtin).
// ---------------------------------------------------------------------------
__global__ __launch_bounds__(256)
void lwc_apply(const float* __restrict__ x,
               const float* __restrict__ w,
               float* __restrict__ out)
{
    const int tid = threadIdx.x;
    const int tq  = tid & 15;
    const int rl  = tid >> 4;           // 0..15
    const int t0  = blockIdx.x * 64;
    const int h   = blockIdx.y & 15;
    const int rq  = blockIdx.y >> 4;    // 0..3
    const int b   = blockIdx.z;

    const int tb = t0 + tq * 4;

    // 15 taps for (b, h, tb..tb+3)  — broadcast across the 4 channel lanes
    const float* wb = w + (((size_t)b * Hn + h) * Kn) * Tn + tb;
    float4 wreg[15];
#pragma unroll
    for (int k = 0; k < 15; ++k)
        wreg[k] = *reinterpret_cast<const float4*>(wb + (size_t)k * Tn);

    const int c = (rq * 16 + rl) * Hn + h;
    const float* xrow = x + ((size_t)b * Cn + c) * Tn;
    const int g0 = tb - 8;
    const bool interior = (g0 >= 0) && (g0 + 20 <= Tn);

    float xv[20];
    if (interior) {
        const float4* xp = reinterpret_cast<const float4*>(xrow + g0);
#pragma unroll
        for (int q = 0; q < 5; ++q) {
            const float4 a = xp[q];
            xv[4 * q + 0] = a.x; xv[4 * q + 1] = a.y;
            xv[4 * q + 2] = a.z; xv[4 * q + 3] = a.w;
        }
    } else {
#pragma unroll
        for (int i = 0; i < 20; ++i) {
            const int g = g0 + i;
            xv[i] = ((unsigned)g < (unsigned)Tn) ? xrow[g] : 0.f;
        }
    }

    // out(t = tb+j) = sum_k wreg[k][j] * x[t+k-7] = xv[j+k+1]
    float ox = 0.f, oy = 0.f, oz = 0.f, ow = 0.f;
#pragma unroll
    for (int k = 0; k < 15; ++k) {
        ox += wreg[k].x * xv[k + 1];
        oy += wreg[k].y * xv[k + 2];
        oz += wreg[k].z * xv[k + 3];
        ow += wreg[k].w * xv[k + 4];
    }
    f32x4 o = {ox, oy, oz, ow};
    __builtin_nontemporal_store(
        o, reinterpret_cast<f32x4*>(out + ((size_t)b * Cn + c) * Tn + tb));
}

// ---------------------------------------------------------------------------
// kernel_launch — scratch plan (round-4 proven):
//   d_ws  : w (B,H,K,T) f32 = 30 MiB
//   d_out : [0,512K) W' bf16 (consumed by fused_weights before apply
//           overwrites d_out; stream-ordered)
// ---------------------------------------------------------------------------
extern "C" void kernel_launch(void* const* d_in, const int* in_sizes, int n_in,
                              void* d_out, int out_size, void* d_ws, size_t ws_size,
                              hipStream_t stream)
{
    const float* x = (const float*)d_in[0];
    const float* W = (const float*)d_in[1];
    float* out     = (float*)d_out;
    float* wks     = (float*)d_ws;

    unsigned short* Wp = (unsigned short*)d_out;   // 512 KiB scratch in d_out

    lwc_wpad<<<dim3(Fp * Cn / 4 / 256), 256, 0, stream>>>(W, Wp);

    dim3 gF(Tn / 64, Bn);              // (64, 8)
    lwc_fused_weights<<<gF, 256, 0, stream>>>(x, Wp, wks);

    dim3 gB(Tn / 64, Hn * 4, Bn);      // (64, 64, 8) = 32768 blocks
    lwc_apply<<<gB, 256, 0, stream>>>(x, wks, out);
}

// Round 8
// 131.065 us; speedup vs baseline: 1.1713x; 1.1713x over previous
//
#include <hip/hip_runtime.h>
#include <hip/hip_bf16.h>

// Problem constants
constexpr int Bn  = 8;
constexpr int Cn  = 1024;
constexpr int Tn  = 4096;
constexpr int Hn  = 16;
constexpr int Kn  = 15;
constexpr int Fp  = 256;   // padded f dim: row = h*16 + k, k==15 is zero pad

typedef __attribute__((ext_vector_type(8))) short    bf16x8;
typedef __attribute__((ext_vector_type(4))) float    f32x4;

static __device__ __forceinline__ unsigned short f2bf(float f) {
    __hip_bfloat16 h = __float2bfloat16(f);   // round-to-nearest-even
    return *reinterpret_cast<unsigned short*>(&h);
}

// ---------------------------------------------------------------------------
// P1: build padded bf16 W' (256 x 1024) from W (240 x 1024) f32.
// ---------------------------------------------------------------------------
__global__ __launch_bounds__(256)
void lwc_wpad(const float* __restrict__ W, unsigned short* __restrict__ Wp)
{
    const int idx = (blockIdx.x * 256 + threadIdx.x) * 4;  // over 256*1024
    const int m = idx >> 10, c = idx & 1023;
    const int h = m >> 4, k = m & 15;
    float4 v = make_float4(0.f, 0.f, 0.f, 0.f);
    if (k < 15)
        v = *reinterpret_cast<const float4*>(W + ((size_t)(h * 15 + k)) * Cn + c);
    ushort4 o;
    o.x = f2bf(v.x); o.y = f2bf(v.y); o.z = f2bf(v.z); o.w = f2bf(v.w);
    *reinterpret_cast<ushort4*>(Wp + idx) = o;
}

// ---------------------------------------------------------------------------
// Fused transpose + GEMM + softmax (round-4 verified version, unchanged).
// grid (Tn/64, Bn), block 256 (4 waves). w (B,H,K,T) f32 -> d_ws.
// ---------------------------------------------------------------------------
__global__ __launch_bounds__(256)
void lwc_fused_weights(const float* __restrict__ x,
                       const unsigned short* __restrict__ Wp,
                       float* __restrict__ wout)
{
    __shared__ __align__(16) unsigned short xs[2 * 16 * 64 * 8];   // 32 KiB

    const int tid  = threadIdx.x;
    const int lane = tid & 63;
    const int wv   = tid >> 6;
    const int t0   = blockIdx.x * 64;
    const int b    = blockIdx.y;

    const int lr = lane & 15;
    const int lg = lane >> 4;

    const int tcell = tid & 15;
    const int coct  = tid >> 4;
    const float* xbase = x + (size_t)b * Cn * Tn + t0 + tcell * 4;

    f32x4 acc[4][4];
#pragma unroll
    for (int i = 0; i < 4; ++i)
#pragma unroll
        for (int j = 0; j < 4; ++j) acc[i][j] = (f32x4){0.f, 0.f, 0.f, 0.f};

    float4 ld[8];
#pragma unroll
    for (int j = 0; j < 8; ++j)
        ld[j] = *reinterpret_cast<const float4*>(
            xbase + (size_t)(coct * 8 + j) * Tn);

    const unsigned short* Abase = Wp + ((size_t)(wv * 64 + lr)) * Cn + lg * 8;
    const int lrx0 = lr ^ lg;
    unsigned short* wrow = xs + coct * 512;
    const int csw = coct & 7;

#pragma unroll 1
    for (int ck = 0; ck < 8; ++ck) {
        const int buf = (ck & 1) * 8192;

        float cf[8][4];
#pragma unroll
        for (int j = 0; j < 8; ++j) {
            cf[j][0] = ld[j].x; cf[j][1] = ld[j].y;
            cf[j][2] = ld[j].z; cf[j][3] = ld[j].w;
        }
#pragma unroll
        for (int tt = 0; tt < 4; ++tt) {
            const int slotw = (tcell * 4 + tt) ^ csw;
            bf16x8 pk;
#pragma unroll
            for (int j = 0; j < 8; ++j) pk[j] = (short)f2bf(cf[j][tt]);
            *reinterpret_cast<bf16x8*>(wrow + buf + slotw * 8) = pk;
        }

        __syncthreads();

        if (ck < 7) {
#pragma unroll
            for (int j = 0; j < 8; ++j)
                ld[j] = *reinterpret_cast<const float4*>(
                    xbase + (size_t)((ck + 1) * 128 + coct * 8 + j) * Tn);
        }

        const unsigned short* Apc = Abase + ck * 128;
#pragma unroll
        for (int ks = 0; ks < 4; ++ks) {
            bf16x8 af[4], bfr[4];
            const unsigned short* ap = Apc + ks * 32;
#pragma unroll
            for (int mi = 0; mi < 4; ++mi)
                af[mi] = *reinterpret_cast<const bf16x8*>(ap + (size_t)mi * 16 * Cn);
            const int lrx = lrx0 ^ ((ks & 1) << 2);
            const unsigned short* bp = xs + buf + (ks * 4 + lg) * 512 + lrx * 8;
#pragma unroll
            for (int ni = 0; ni < 4; ++ni)
                bfr[ni] = *reinterpret_cast<const bf16x8*>(bp + ni * 128);
#pragma unroll
            for (int mi = 0; mi < 4; ++mi)
#pragma unroll
                for (int ni = 0; ni < 4; ++ni)
                    acc[mi][ni] = __builtin_amdgcn_mfma_f32_16x16x32_bf16(
                        af[mi], bfr[ni], acc[mi][ni], 0, 0, 0);
        }
    }

    const int tcol = lane & 15;
#pragma unroll
    for (int mi = 0; mi < 4; ++mi) {
        const int h = wv * 4 + mi;
        float* hbase = wout + (((size_t)b * Hn + h) * Kn) * Tn + t0;
#pragma unroll
        for (int ni = 0; ni < 4; ++ni) {
            f32x4 v = acc[mi][ni];
            float mx = -3.0e38f;
#pragma unroll
            for (int r = 0; r < 4; ++r)
                if (lg * 4 + r < 15) mx = fmaxf(mx, v[r]);
            mx = fmaxf(mx, __shfl_xor(mx, 16));
            mx = fmaxf(mx, __shfl_xor(mx, 32));
            float e[4], s = 0.f;
#pragma unroll
            for (int r = 0; r < 4; ++r) {
                const int k = lg * 4 + r;
                e[r] = (k < 15) ? __expf(v[r] - mx) : 0.f;
                s += e[r];
            }
            s += __shfl_xor(s, 16);
            s += __shfl_xor(s, 32);
            const float inv = 1.f / s;
#pragma unroll
            for (int r = 0; r < 4; ++r) {
                const int k = lg * 4 + r;
                if (k < 15)
                    hbase[(size_t)k * Tn + ni * 16 + tcol] = e[r] * inv;
            }
        }
    }
}

// ---------------------------------------------------------------------------
// Kernel B v3: whole head (64 channels) inside ONE block (w from HBM once),
// parallelism from block count: grid (Tn/64, Hn, Bn) = 8192 blocks (4x wave
// capacity). Thread = (cgrp = tid>>4, quad = tid&15): 4 channels x 4 t each,
// channel iterations fully unrolled & independent -> ~20 loads in flight.
// ---------------------------------------------------------------------------
__global__ __launch_bounds__(256)
void lwc_apply(const float* __restrict__ x,
               const float* __restrict__ w,
               float* __restrict__ out)
{
    const int tid  = threadIdx.x;
    const int tq   = tid & 15;
    const int cgrp = tid >> 4;          // 0..15
    const int t0   = blockIdx.x * 64;
    const int h    = blockIdx.y;
    const int b    = blockIdx.z;

    const int tb = t0 + tq * 4;

    // 15 taps for (b, h, tb..tb+3) — same addresses across the 16 cgrps
    const float* wb = w + (((size_t)b * Hn + h) * Kn) * Tn + tb;
    float4 wreg[15];
#pragma unroll
    for (int k = 0; k < 15; ++k)
        wreg[k] = *reinterpret_cast<const float4*>(wb + (size_t)k * Tn);

    const int g0 = tb - 8;
    const bool interior = (g0 >= 0) && (g0 + 20 <= Tn);
    const float* xb = x + (size_t)b * Cn * Tn;
    float*       ob = out + (size_t)b * Cn * Tn;

#pragma unroll
    for (int j = 0; j < 4; ++j) {
        const int c = (cgrp * 4 + j) * Hn + h;
        const float* xrow = xb + (size_t)c * Tn;

        float xv[20];
        if (interior) {
            const float4* xp = reinterpret_cast<const float4*>(xrow + g0);
#pragma unroll
            for (int q = 0; q < 5; ++q) {
                const float4 a = xp[q];
                xv[4 * q + 0] = a.x; xv[4 * q + 1] = a.y;
                xv[4 * q + 2] = a.z; xv[4 * q + 3] = a.w;
            }
        } else {
#pragma unroll
            for (int i = 0; i < 20; ++i) {
                const int g = g0 + i;
                xv[i] = ((unsigned)g < (unsigned)Tn) ? xrow[g] : 0.f;
            }
        }

        // out(t = tb+jj) = sum_k wreg[k][jj] * xv[jj+k+1]
        float ox = 0.f, oy = 0.f, oz = 0.f, ow = 0.f;
#pragma unroll
        for (int k = 0; k < 15; ++k) {
            ox += wreg[k].x * xv[k + 1];
            oy += wreg[k].y * xv[k + 2];
            oz += wreg[k].z * xv[k + 3];
            ow += wreg[k].w * xv[k + 4];
        }
        f32x4 o = {ox, oy, oz, ow};
        __builtin_nontemporal_store(
            o, reinterpret_cast<f32x4*>(ob + (size_t)c * Tn + tb));
    }
}

// ---------------------------------------------------------------------------
// kernel_launch — scratch plan (round-4 proven):
//   d_ws  : w (B,H,K,T) f32 = 30 MiB
//   d_out : [0,512K) W' bf16 (consumed by fused_weights before apply
//           overwrites d_out; stream-ordered)
// ---------------------------------------------------------------------------
extern "C" void kernel_launch(void* const* d_in, const int* in_sizes, int n_in,
                              void* d_out, int out_size, void* d_ws, size_t ws_size,
                              hipStream_t stream)
{
    const float* x = (const float*)d_in[0];
    const float* W = (const float*)d_in[1];
    float* out     = (float*)d_out;
    float* wks     = (float*)d_ws;

    unsigned short* Wp = (unsigned short*)d_out;   // 512 KiB scratch in d_out

    lwc_wpad<<<dim3(Fp * Cn / 4 / 256), 256, 0, stream>>>(W, Wp);

    dim3 gF(Tn / 64, Bn);              // (64, 8)
    lwc_fused_weights<<<gF, 256, 0, stream>>>(x, Wp, wks);

    dim3 gB(Tn / 64, Hn, Bn);          // (64, 16, 8) = 8192 blocks
    lwc_apply<<<gB, 256, 0, stream>>>(x, wks, out);
}

// Round 9
// 120.634 us; speedup vs baseline: 1.2726x; 1.0865x over previous
//
#include <hip/hip_runtime.h>
#include <hip/hip_bf16.h>

// Problem constants
constexpr int Bn  = 8;
constexpr int Cn  = 1024;
constexpr int Tn  = 4096;
constexpr int Hn  = 16;
constexpr int Kn  = 15;
constexpr int Fp  = 256;   // padded f dim: row = h*16 + k, k==15 is zero pad

typedef __attribute__((ext_vector_type(8))) short    bf16x8;
typedef __attribute__((ext_vector_type(4))) float    f32x4;

static __device__ __forceinline__ unsigned short f2bf(float f) {
    __hip_bfloat16 h = __float2bfloat16(f);   // round-to-nearest-even
    return *reinterpret_cast<unsigned short*>(&h);
}

// ---------------------------------------------------------------------------
// P1: build padded bf16 W' (256 x 1024) from W (240 x 1024) f32.
// ---------------------------------------------------------------------------
__global__ __launch_bounds__(256)
void lwc_wpad(const float* __restrict__ W, unsigned short* __restrict__ Wp)
{
    const int idx = (blockIdx.x * 256 + threadIdx.x) * 4;  // over 256*1024
    const int m = idx >> 10, c = idx & 1023;
    const int h = m >> 4, k = m & 15;
    float4 v = make_float4(0.f, 0.f, 0.f, 0.f);
    if (k < 15)
        v = *reinterpret_cast<const float4*>(W + ((size_t)(h * 15 + k)) * Cn + c);
    ushort4 o;
    o.x = f2bf(v.x); o.y = f2bf(v.y); o.z = f2bf(v.z); o.w = f2bf(v.w);
    *reinterpret_cast<ushort4*>(Wp + idx) = o;
}

// ---------------------------------------------------------------------------
// Fused transpose + GEMM + softmax. Round-4 structure; w now stored BF16
// (B,H,K,T) -> d_ws (15 MiB). grid (Tn/64, Bn), block 256 (4 waves).
// ---------------------------------------------------------------------------
__global__ __launch_bounds__(256)
void lwc_fused_weights(const float* __restrict__ x,
                       const unsigned short* __restrict__ Wp,
                       unsigned short* __restrict__ wout)
{
    __shared__ __align__(16) unsigned short xs[2 * 16 * 64 * 8];   // 32 KiB

    const int tid  = threadIdx.x;
    const int lane = tid & 63;
    const int wv   = tid >> 6;
    const int t0   = blockIdx.x * 64;
    const int b    = blockIdx.y;

    const int lr = lane & 15;
    const int lg = lane >> 4;

    const int tcell = tid & 15;
    const int coct  = tid >> 4;
    const float* xbase = x + (size_t)b * Cn * Tn + t0 + tcell * 4;

    f32x4 acc[4][4];
#pragma unroll
    for (int i = 0; i < 4; ++i)
#pragma unroll
        for (int j = 0; j < 4; ++j) acc[i][j] = (f32x4){0.f, 0.f, 0.f, 0.f};

    float4 ld[8];
#pragma unroll
    for (int j = 0; j < 8; ++j)
        ld[j] = *reinterpret_cast<const float4*>(
            xbase + (size_t)(coct * 8 + j) * Tn);

    const unsigned short* Abase = Wp + ((size_t)(wv * 64 + lr)) * Cn + lg * 8;
    const int lrx0 = lr ^ lg;
    unsigned short* wrow = xs + coct * 512;
    const int csw = coct & 7;

#pragma unroll 1
    for (int ck = 0; ck < 8; ++ck) {
        const int buf = (ck & 1) * 8192;

        float cf[8][4];
#pragma unroll
        for (int j = 0; j < 8; ++j) {
            cf[j][0] = ld[j].x; cf[j][1] = ld[j].y;
            cf[j][2] = ld[j].z; cf[j][3] = ld[j].w;
        }
#pragma unroll
        for (int tt = 0; tt < 4; ++tt) {
            const int slotw = (tcell * 4 + tt) ^ csw;
            bf16x8 pk;
#pragma unroll
            for (int j = 0; j < 8; ++j) pk[j] = (short)f2bf(cf[j][tt]);
            *reinterpret_cast<bf16x8*>(wrow + buf + slotw * 8) = pk;
        }

        __syncthreads();

        if (ck < 7) {
#pragma unroll
            for (int j = 0; j < 8; ++j)
                ld[j] = *reinterpret_cast<const float4*>(
                    xbase + (size_t)((ck + 1) * 128 + coct * 8 + j) * Tn);
        }

        const unsigned short* Apc = Abase + ck * 128;
#pragma unroll
        for (int ks = 0; ks < 4; ++ks) {
            bf16x8 af[4], bfr[4];
            const unsigned short* ap = Apc + ks * 32;
#pragma unroll
            for (int mi = 0; mi < 4; ++mi)
                af[mi] = *reinterpret_cast<const bf16x8*>(ap + (size_t)mi * 16 * Cn);
            const int lrx = lrx0 ^ ((ks & 1) << 2);
            const unsigned short* bp = xs + buf + (ks * 4 + lg) * 512 + lrx * 8;
#pragma unroll
            for (int ni = 0; ni < 4; ++ni)
                bfr[ni] = *reinterpret_cast<const bf16x8*>(bp + ni * 128);
#pragma unroll
            for (int mi = 0; mi < 4; ++mi)
#pragma unroll
                for (int ni = 0; ni < 4; ++ni)
                    acc[mi][ni] = __builtin_amdgcn_mfma_f32_16x16x32_bf16(
                        af[mi], bfr[ni], acc[mi][ni], 0, 0, 0);
        }
    }

    const int tcol = lane & 15;
#pragma unroll
    for (int mi = 0; mi < 4; ++mi) {
        const int h = wv * 4 + mi;
        unsigned short* hbase = wout + (((size_t)b * Hn + h) * Kn) * Tn + t0;
#pragma unroll
        for (int ni = 0; ni < 4; ++ni) {
            f32x4 v = acc[mi][ni];
            float mx = -3.0e38f;
#pragma unroll
            for (int r = 0; r < 4; ++r)
                if (lg * 4 + r < 15) mx = fmaxf(mx, v[r]);
            mx = fmaxf(mx, __shfl_xor(mx, 16));
            mx = fmaxf(mx, __shfl_xor(mx, 32));
            float e[4], s = 0.f;
#pragma unroll
            for (int r = 0; r < 4; ++r) {
                const int k = lg * 4 + r;
                e[r] = (k < 15) ? __expf(v[r] - mx) : 0.f;
                s += e[r];
            }
            s += __shfl_xor(s, 16);
            s += __shfl_xor(s, 32);
            const float inv = 1.f / s;
#pragma unroll
            for (int r = 0; r < 4; ++r) {
                const int k = lg * 4 + r;
                if (k < 15)
                    hbase[(size_t)k * Tn + ni * 16 + tcol] = f2bf(e[r] * inv);
            }
        }
    }
}

// ---------------------------------------------------------------------------
// Kernel B v4: 8 t per thread (halved x-load amplification), bf16 w (halved
// w bytes). Whole head per block (w fetched once per (b,h,t-chunk)).
// grid (Tn/128, Hn, Bn) = (32,16,8) = 4096 blocks.
// thread: tq = tid&15 -> 8 t's; cgrp = tid>>4 -> 4 channels.
// ---------------------------------------------------------------------------
__global__ __launch_bounds__(256)
void lwc_apply(const float* __restrict__ x,
               const unsigned short* __restrict__ w,
               float* __restrict__ out)
{
    const int tid  = threadIdx.x;
    const int tq   = tid & 15;
    const int cgrp = tid >> 4;          // 0..15
    const int t0   = blockIdx.x * 128;
    const int h    = blockIdx.y;
    const int b    = blockIdx.z;
    const int tb   = t0 + tq * 8;

    // 15 taps x 8 t, packed bf16 (15 x 16B = 60 VGPR)
    const unsigned short* wb = w + (((size_t)b * Hn + h) * Kn) * Tn + tb;
    bf16x8 wk[15];
#pragma unroll
    for (int k = 0; k < 15; ++k)
        wk[k] = *reinterpret_cast<const bf16x8*>(wb + (size_t)k * Tn);

    const int g0 = tb - 8;                       // window [tb-8, tb+16)
    const bool interior = (g0 >= 0) && (g0 + 24 <= Tn);
    const float* xb = x + (size_t)b * Cn * Tn;
    float*       ob = out + (size_t)b * Cn * Tn;

#pragma unroll
    for (int j = 0; j < 4; ++j) {
        const int c = (cgrp * 4 + j) * Hn + h;
        const float* xrow = xb + (size_t)c * Tn;

        float xv[24];
        if (interior) {
            const float4* xp = reinterpret_cast<const float4*>(xrow + g0);
#pragma unroll
            for (int q = 0; q < 6; ++q) {
                const float4 a = xp[q];
                xv[4 * q + 0] = a.x; xv[4 * q + 1] = a.y;
                xv[4 * q + 2] = a.z; xv[4 * q + 3] = a.w;
            }
        } else {
#pragma unroll
            for (int i = 0; i < 24; ++i) {
                const int g = g0 + i;
                xv[i] = ((unsigned)g < (unsigned)Tn) ? xrow[g] : 0.f;
            }
        }

        // out(t = tb+jj) = sum_k w[k][tb+jj] * x[t+k-7] = xv[jj+k+1]
        float o8[8] = {0.f, 0.f, 0.f, 0.f, 0.f, 0.f, 0.f, 0.f};
#pragma unroll
        for (int k = 0; k < 15; ++k) {
#pragma unroll
            for (int jj = 0; jj < 8; ++jj) {
                const unsigned int u =
                    ((unsigned int)(unsigned short)wk[k][jj]) << 16;
                o8[jj] += __uint_as_float(u) * xv[jj + k + 1];
            }
        }

        f32x4 o0 = {o8[0], o8[1], o8[2], o8[3]};
        f32x4 o1 = {o8[4], o8[5], o8[6], o8[7]};
        float* dst = ob + (size_t)c * Tn + tb;
        __builtin_nontemporal_store(o0, reinterpret_cast<f32x4*>(dst));
        __builtin_nontemporal_store(o1, reinterpret_cast<f32x4*>(dst + 4));
    }
}

// ---------------------------------------------------------------------------
// kernel_launch — scratch plan:
//   d_ws  : w (B,H,K,T) BF16 = 15 MiB
//   d_out : [0,512K) W' bf16 (consumed by fused_weights before apply
//           overwrites d_out; stream-ordered)
// ---------------------------------------------------------------------------
extern "C" void kernel_launch(void* const* d_in, const int* in_sizes, int n_in,
                              void* d_out, int out_size, void* d_ws, size_t ws_size,
                              hipStream_t stream)
{
    const float* x = (const float*)d_in[0];
    const float* W = (const float*)d_in[1];
    float* out     = (float*)d_out;
    unsigned short* wks = (unsigned short*)d_ws;   // bf16 w workspace

    unsigned short* Wp = (unsigned short*)d_out;   // 512 KiB scratch in d_out

    lwc_wpad<<<dim3(Fp * Cn / 4 / 256), 256, 0, stream>>>(W, Wp);

    dim3 gF(Tn / 64, Bn);              // (64, 8)
    lwc_fused_weights<<<gF, 256, 0, stream>>>(x, Wp, wks);

    dim3 gB(Tn / 128, Hn, Bn);         // (32, 16, 8) = 4096 blocks
    lwc_apply<<<gB, 256, 0, stream>>>(x, wks, out);
}

// Round 10
// 107.856 us; speedup vs baseline: 1.4234x; 1.1185x over previous
//
#include <hip/hip_runtime.h>
#include <hip/hip_bf16.h>

// Problem constants
constexpr int Bn  = 8;
constexpr int Cn  = 1024;
constexpr int Tn  = 4096;
constexpr int Hn  = 16;
constexpr int Kn  = 15;
constexpr int Fp  = 256;   // padded f dim: row = h*16 + k, k==15 is zero pad

typedef __attribute__((ext_vector_type(8))) short    bf16x8;
typedef __attribute__((ext_vector_type(4))) float    f32x4;

static __device__ __forceinline__ unsigned short f2bf(float f) {
    __hip_bfloat16 h = __float2bfloat16(f);   // round-to-nearest-even
    return *reinterpret_cast<unsigned short*>(&h);
}

// ---------------------------------------------------------------------------
// P1: build padded bf16 W' (256 x 1024) from W (240 x 1024) f32.
// ---------------------------------------------------------------------------
__global__ __launch_bounds__(256)
void lwc_wpad(const float* __restrict__ W, unsigned short* __restrict__ Wp)
{
    const int idx = (blockIdx.x * 256 + threadIdx.x) * 4;  // over 256*1024
    const int m = idx >> 10, c = idx & 1023;
    const int h = m >> 4, k = m & 15;
    float4 v = make_float4(0.f, 0.f, 0.f, 0.f);
    if (k < 15)
        v = *reinterpret_cast<const float4*>(W + ((size_t)(h * 15 + k)) * Cn + c);
    ushort4 o;
    o.x = f2bf(v.x); o.y = f2bf(v.y); o.z = f2bf(v.z); o.w = f2bf(v.w);
    *reinterpret_cast<ushort4*>(Wp + idx) = o;
}

// ---------------------------------------------------------------------------
// Fused transpose + GEMM + softmax; w stored BF16 (B,H,K,T) -> d_ws (15 MiB).
// 1-D grid 512, XCD-chunk swizzled: work = (bid%8)*64 + bid/8 so one XCD
// owns all 64 t-tiles of one b -> x rows covered sequentially per XCD L2.
// ---------------------------------------------------------------------------
__global__ __launch_bounds__(256)
void lwc_fused_weights(const float* __restrict__ x,
                       const unsigned short* __restrict__ Wp,
                       unsigned short* __restrict__ wout)
{
    __shared__ __align__(16) unsigned short xs[2 * 16 * 64 * 8];   // 32 KiB

    const int flat = blockIdx.x;                    // 0..511
    const int work = (flat & 7) * 64 + (flat >> 3); // chunked XCD swizzle
    const int t0   = (work & 63) * 64;
    const int b    = work >> 6;

    const int tid  = threadIdx.x;
    const int lane = tid & 63;
    const int wv   = tid >> 6;

    const int lr = lane & 15;
    const int lg = lane >> 4;

    const int tcell = tid & 15;
    const int coct  = tid >> 4;
    const float* xbase = x + (size_t)b * Cn * Tn + t0 + tcell * 4;

    f32x4 acc[4][4];
#pragma unroll
    for (int i = 0; i < 4; ++i)
#pragma unroll
        for (int j = 0; j < 4; ++j) acc[i][j] = (f32x4){0.f, 0.f, 0.f, 0.f};

    float4 ld[8];
#pragma unroll
    for (int j = 0; j < 8; ++j)
        ld[j] = *reinterpret_cast<const float4*>(
            xbase + (size_t)(coct * 8 + j) * Tn);

    const unsigned short* Abase = Wp + ((size_t)(wv * 64 + lr)) * Cn + lg * 8;
    const int lrx0 = lr ^ lg;
    unsigned short* wrow = xs + coct * 512;
    const int csw = coct & 7;

#pragma unroll 1
    for (int ck = 0; ck < 8; ++ck) {
        const int buf = (ck & 1) * 8192;

        float cf[8][4];
#pragma unroll
        for (int j = 0; j < 8; ++j) {
            cf[j][0] = ld[j].x; cf[j][1] = ld[j].y;
            cf[j][2] = ld[j].z; cf[j][3] = ld[j].w;
        }
#pragma unroll
        for (int tt = 0; tt < 4; ++tt) {
            const int slotw = (tcell * 4 + tt) ^ csw;
            bf16x8 pk;
#pragma unroll
            for (int j = 0; j < 8; ++j) pk[j] = (short)f2bf(cf[j][tt]);
            *reinterpret_cast<bf16x8*>(wrow + buf + slotw * 8) = pk;
        }

        __syncthreads();

        if (ck < 7) {
#pragma unroll
            for (int j = 0; j < 8; ++j)
                ld[j] = *reinterpret_cast<const float4*>(
                    xbase + (size_t)((ck + 1) * 128 + coct * 8 + j) * Tn);
        }

        const unsigned short* Apc = Abase + ck * 128;
#pragma unroll
        for (int ks = 0; ks < 4; ++ks) {
            bf16x8 af[4], bfr[4];
            const unsigned short* ap = Apc + ks * 32;
#pragma unroll
            for (int mi = 0; mi < 4; ++mi)
                af[mi] = *reinterpret_cast<const bf16x8*>(ap + (size_t)mi * 16 * Cn);
            const int lrx = lrx0 ^ ((ks & 1) << 2);
            const unsigned short* bp = xs + buf + (ks * 4 + lg) * 512 + lrx * 8;
#pragma unroll
            for (int ni = 0; ni < 4; ++ni)
                bfr[ni] = *reinterpret_cast<const bf16x8*>(bp + ni * 128);
#pragma unroll
            for (int mi = 0; mi < 4; ++mi)
#pragma unroll
                for (int ni = 0; ni < 4; ++ni)
                    acc[mi][ni] = __builtin_amdgcn_mfma_f32_16x16x32_bf16(
                        af[mi], bfr[ni], acc[mi][ni], 0, 0, 0);
        }
    }

    const int tcol = lane & 15;
#pragma unroll
    for (int mi = 0; mi < 4; ++mi) {
        const int h = wv * 4 + mi;
        unsigned short* hbase = wout + (((size_t)b * Hn + h) * Kn) * Tn + t0;
#pragma unroll
        for (int ni = 0; ni < 4; ++ni) {
            f32x4 v = acc[mi][ni];
            float mx = -3.0e38f;
#pragma unroll
            for (int r = 0; r < 4; ++r)
                if (lg * 4 + r < 15) mx = fmaxf(mx, v[r]);
            mx = fmaxf(mx, __shfl_xor(mx, 16));
            mx = fmaxf(mx, __shfl_xor(mx, 32));
            float e[4], s = 0.f;
#pragma unroll
            for (int r = 0; r < 4; ++r) {
                const int k = lg * 4 + r;
                e[r] = (k < 15) ? __expf(v[r] - mx) : 0.f;
                s += e[r];
            }
            s += __shfl_xor(s, 16);
            s += __shfl_xor(s, 32);
            const float inv = 1.f / s;
#pragma unroll
            for (int r = 0; r < 4; ++r) {
                const int k = lg * 4 + r;
                if (k < 15)
                    hbase[(size_t)k * Tn + ni * 16 + tcol] = f2bf(e[r] * inv);
            }
        }
    }
}

// ---------------------------------------------------------------------------
// Kernel B v5: t-chunk 256 (per-row contiguous read ~1.1 KB, halo 4%),
// head-per-block w sharing, XCD-chunk swizzle (one XCD owns one b).
// 1-D grid 2048: work = tc + 16*h + 256*b. Thread = (tq = tid&31 -> 8 t's,
// cgrp = tid>>5 -> 8 channels). bf16 w taps (15 x bf16x8 regs).
// ---------------------------------------------------------------------------
__global__ __launch_bounds__(256)
void lwc_apply(const float* __restrict__ x,
               const unsigned short* __restrict__ w,
               float* __restrict__ out)
{
    const int flat = blockIdx.x;                       // 0..2047
    const int work = (flat & 7) * 256 + (flat >> 3);   // chunked XCD swizzle
    const int t0   = (work & 15) * 256;
    const int h    = (work >> 4) & 15;
    const int b    = work >> 8;

    const int tid  = threadIdx.x;
    const int tq   = tid & 31;          // 0..31 -> 8 t's each
    const int cgrp = tid >> 5;          // 0..7  -> 8 channels each
    const int tb   = t0 + tq * 8;

    // 15 taps x 8 t, packed bf16 (60 VGPR), shared by this head's 64 channels
    const unsigned short* wb = w + (((size_t)b * Hn + h) * Kn) * Tn + tb;
    bf16x8 wk[15];
#pragma unroll
    for (int k = 0; k < 15; ++k)
        wk[k] = *reinterpret_cast<const bf16x8*>(wb + (size_t)k * Tn);

    const int g0 = tb - 8;                       // window [tb-8, tb+16)
    const bool interior = (g0 >= 0) && (g0 + 24 <= Tn);
    const float* xb = x + (size_t)b * Cn * Tn;
    float*       ob = out + (size_t)b * Cn * Tn;

#pragma unroll
    for (int j = 0; j < 8; ++j) {
        const int c = (cgrp * 8 + j) * Hn + h;
        const float* xrow = xb + (size_t)c * Tn;

        float xv[24];
        if (interior) {
            const float4* xp = reinterpret_cast<const float4*>(xrow + g0);
#pragma unroll
            for (int q = 0; q < 6; ++q) {
                const float4 a = xp[q];
                xv[4 * q + 0] = a.x; xv[4 * q + 1] = a.y;
                xv[4 * q + 2] = a.z; xv[4 * q + 3] = a.w;
            }
        } else {
#pragma unroll
            for (int i = 0; i < 24; ++i) {
                const int g = g0 + i;
                xv[i] = ((unsigned)g < (unsigned)Tn) ? xrow[g] : 0.f;
            }
        }

        // out(t = tb+jj) = sum_k w[k][tb+jj] * x[t+k-7] = xv[jj+k+1]
        float o8[8] = {0.f, 0.f, 0.f, 0.f, 0.f, 0.f, 0.f, 0.f};
#pragma unroll
        for (int k = 0; k < 15; ++k) {
#pragma unroll
            for (int jj = 0; jj < 8; ++jj) {
                const unsigned int u =
                    ((unsigned int)(unsigned short)wk[k][jj]) << 16;
                o8[jj] += __uint_as_float(u) * xv[jj + k + 1];
            }
        }

        f32x4 o0 = {o8[0], o8[1], o8[2], o8[3]};
        f32x4 o1 = {o8[4], o8[5], o8[6], o8[7]};
        float* dst = ob + (size_t)c * Tn + tb;
        __builtin_nontemporal_store(o0, reinterpret_cast<f32x4*>(dst));
        __builtin_nontemporal_store(o1, reinterpret_cast<f32x4*>(dst + 4));
    }
}

// ---------------------------------------------------------------------------
// kernel_launch — scratch plan:
//   d_ws  : w (B,H,K,T) BF16 = 15 MiB
//   d_out : [0,512K) W' bf16 (consumed by fused_weights before apply
//           overwrites d_out; stream-ordered)
// ---------------------------------------------------------------------------
extern "C" void kernel_launch(void* const* d_in, const int* in_sizes, int n_in,
                              void* d_out, int out_size, void* d_ws, size_t ws_size,
                              hipStream_t stream)
{
    const float* x = (const float*)d_in[0];
    const float* W = (const float*)d_in[1];
    float* out     = (float*)d_out;
    unsigned short* wks = (unsigned short*)d_ws;   // bf16 w workspace

    unsigned short* Wp = (unsigned short*)d_out;   // 512 KiB scratch in d_out

    lwc_wpad<<<dim3(Fp * Cn / 4 / 256), 256, 0, stream>>>(W, Wp);

    lwc_fused_weights<<<dim3(512), 256, 0, stream>>>(x, Wp, wks);

    lwc_apply<<<dim3(2048), 256, 0, stream>>>(x, wks, out);
}

// Round 11
// 104.444 us; speedup vs baseline: 1.4699x; 1.0327x over previous
//
#include <hip/hip_runtime.h>
#include <hip/hip_bf16.h>

// Problem constants
constexpr int Bn  = 8;
constexpr int Cn  = 1024;
constexpr int Tn  = 4096;
constexpr int Hn  = 16;
constexpr int Kn  = 15;
constexpr int Fp  = 256;   // padded f dim: row = h*16 + k, k==15 is zero pad

typedef __attribute__((ext_vector_type(8))) short    bf16x8;
typedef __attribute__((ext_vector_type(4))) float    f32x4;

static __device__ __forceinline__ unsigned short f2bf(float f) {
    __hip_bfloat16 h = __float2bfloat16(f);   // round-to-nearest-even
    return *reinterpret_cast<unsigned short*>(&h);
}

// ---------------------------------------------------------------------------
// P1: build padded bf16 W' (256 x 1024) from W (240 x 1024) f32.
// ---------------------------------------------------------------------------
__global__ __launch_bounds__(256)
void lwc_wpad(const float* __restrict__ W, unsigned short* __restrict__ Wp)
{
    const int idx = (blockIdx.x * 256 + threadIdx.x) * 4;  // over 256*1024
    const int m = idx >> 10, c = idx & 1023;
    const int h = m >> 4, k = m & 15;
    float4 v = make_float4(0.f, 0.f, 0.f, 0.f);
    if (k < 15)
        v = *reinterpret_cast<const float4*>(W + ((size_t)(h * 15 + k)) * Cn + c);
    ushort4 o;
    o.x = f2bf(v.x); o.y = f2bf(v.y); o.z = f2bf(v.z); o.w = f2bf(v.w);
    *reinterpret_cast<ushort4*>(Wp + idx) = o;
}

// ---------------------------------------------------------------------------
// Fused transpose + GEMM + softmax; w stored BF16 (B,H,K,T) -> d_ws (15 MiB).
// REVERTED to round-9 dispatch: 2-D grid (Tn/64, Bn), NO XCD swizzle.
// (Round-10 A/B: b-per-XCD swizzle halved FETCH but doubled dur — 64
// concurrent blocks of one b contending in one XCD's L2/HBM queue.)
// ---------------------------------------------------------------------------
__global__ __launch_bounds__(256)
void lwc_fused_weights(const float* __restrict__ x,
                       const unsigned short* __restrict__ Wp,
                       unsigned short* __restrict__ wout)
{
    __shared__ __align__(16) unsigned short xs[2 * 16 * 64 * 8];   // 32 KiB

    const int tid  = threadIdx.x;
    const int lane = tid & 63;
    const int wv   = tid >> 6;
    const int t0   = blockIdx.x * 64;
    const int b    = blockIdx.y;

    const int lr = lane & 15;
    const int lg = lane >> 4;

    const int tcell = tid & 15;
    const int coct  = tid >> 4;
    const float* xbase = x + (size_t)b * Cn * Tn + t0 + tcell * 4;

    f32x4 acc[4][4];
#pragma unroll
    for (int i = 0; i < 4; ++i)
#pragma unroll
        for (int j = 0; j < 4; ++j) acc[i][j] = (f32x4){0.f, 0.f, 0.f, 0.f};

    float4 ld[8];
#pragma unroll
    for (int j = 0; j < 8; ++j)
        ld[j] = *reinterpret_cast<const float4*>(
            xbase + (size_t)(coct * 8 + j) * Tn);

    const unsigned short* Abase = Wp + ((size_t)(wv * 64 + lr)) * Cn + lg * 8;
    const int lrx0 = lr ^ lg;
    unsigned short* wrow = xs + coct * 512;
    const int csw = coct & 7;

#pragma unroll 1
    for (int ck = 0; ck < 8; ++ck) {
        const int buf = (ck & 1) * 8192;

        float cf[8][4];
#pragma unroll
        for (int j = 0; j < 8; ++j) {
            cf[j][0] = ld[j].x; cf[j][1] = ld[j].y;
            cf[j][2] = ld[j].z; cf[j][3] = ld[j].w;
        }
#pragma unroll
        for (int tt = 0; tt < 4; ++tt) {
            const int slotw = (tcell * 4 + tt) ^ csw;
            bf16x8 pk;
#pragma unroll
            for (int j = 0; j < 8; ++j) pk[j] = (short)f2bf(cf[j][tt]);
            *reinterpret_cast<bf16x8*>(wrow + buf + slotw * 8) = pk;
        }

        __syncthreads();

        if (ck < 7) {
#pragma unroll
            for (int j = 0; j < 8; ++j)
                ld[j] = *reinterpret_cast<const float4*>(
                    xbase + (size_t)((ck + 1) * 128 + coct * 8 + j) * Tn);
        }

        const unsigned short* Apc = Abase + ck * 128;
#pragma unroll
        for (int ks = 0; ks < 4; ++ks) {
            bf16x8 af[4], bfr[4];
            const unsigned short* ap = Apc + ks * 32;
#pragma unroll
            for (int mi = 0; mi < 4; ++mi)
                af[mi] = *reinterpret_cast<const bf16x8*>(ap + (size_t)mi * 16 * Cn);
            const int lrx = lrx0 ^ ((ks & 1) << 2);
            const unsigned short* bp = xs + buf + (ks * 4 + lg) * 512 + lrx * 8;
#pragma unroll
            for (int ni = 0; ni < 4; ++ni)
                bfr[ni] = *reinterpret_cast<const bf16x8*>(bp + ni * 128);
#pragma unroll
            for (int mi = 0; mi < 4; ++mi)
#pragma unroll
                for (int ni = 0; ni < 4; ++ni)
                    acc[mi][ni] = __builtin_amdgcn_mfma_f32_16x16x32_bf16(
                        af[mi], bfr[ni], acc[mi][ni], 0, 0, 0);
        }
    }

    const int tcol = lane & 15;
#pragma unroll
    for (int mi = 0; mi < 4; ++mi) {
        const int h = wv * 4 + mi;
        unsigned short* hbase = wout + (((size_t)b * Hn + h) * Kn) * Tn + t0;
#pragma unroll
        for (int ni = 0; ni < 4; ++ni) {
            f32x4 v = acc[mi][ni];
            float mx = -3.0e38f;
#pragma unroll
            for (int r = 0; r < 4; ++r)
                if (lg * 4 + r < 15) mx = fmaxf(mx, v[r]);
            mx = fmaxf(mx, __shfl_xor(mx, 16));
            mx = fmaxf(mx, __shfl_xor(mx, 32));
            float e[4], s = 0.f;
#pragma unroll
            for (int r = 0; r < 4; ++r) {
                const int k = lg * 4 + r;
                e[r] = (k < 15) ? __expf(v[r] - mx) : 0.f;
                s += e[r];
            }
            s += __shfl_xor(s, 16);
            s += __shfl_xor(s, 32);
            const float inv = 1.f / s;
#pragma unroll
            for (int r = 0; r < 4; ++r) {
                const int k = lg * 4 + r;
                if (k < 15)
                    hbase[(size_t)k * Tn + ni * 16 + tcol] = f2bf(e[r] * inv);
            }
        }
    }
}

// ---------------------------------------------------------------------------
// Kernel B v5 (round-10 winner, UNCHANGED): t-chunk 256, head-per-block w
// sharing, XCD-chunk swizzle (one XCD owns one b). 1-D grid 2048.
// Thread = (tq = tid&31 -> 8 t's, cgrp = tid>>5 -> 8 channels).
// ---------------------------------------------------------------------------
__global__ __launch_bounds__(256)
void lwc_apply(const float* __restrict__ x,
               const unsigned short* __restrict__ w,
               float* __restrict__ out)
{
    const int flat = blockIdx.x;                       // 0..2047
    const int work = (flat & 7) * 256 + (flat >> 3);   // chunked XCD swizzle
    const int t0   = (work & 15) * 256;
    const int h    = (work >> 4) & 15;
    const int b    = work >> 8;

    const int tid  = threadIdx.x;
    const int tq   = tid & 31;          // 0..31 -> 8 t's each
    const int cgrp = tid >> 5;          // 0..7  -> 8 channels each
    const int tb   = t0 + tq * 8;

    // 15 taps x 8 t, packed bf16 (60 VGPR), shared by this head's 64 channels
    const unsigned short* wb = w + (((size_t)b * Hn + h) * Kn) * Tn + tb;
    bf16x8 wk[15];
#pragma unroll
    for (int k = 0; k < 15; ++k)
        wk[k] = *reinterpret_cast<const bf16x8*>(wb + (size_t)k * Tn);

    const int g0 = tb - 8;                       // window [tb-8, tb+16)
    const bool interior = (g0 >= 0) && (g0 + 24 <= Tn);
    const float* xb = x + (size_t)b * Cn * Tn;
    float*       ob = out + (size_t)b * Cn * Tn;

#pragma unroll
    for (int j = 0; j < 8; ++j) {
        const int c = (cgrp * 8 + j) * Hn + h;
        const float* xrow = xb + (size_t)c * Tn;

        float xv[24];
        if (interior) {
            const float4* xp = reinterpret_cast<const float4*>(xrow + g0);
#pragma unroll
            for (int q = 0; q < 6; ++q) {
                const float4 a = xp[q];
                xv[4 * q + 0] = a.x; xv[4 * q + 1] = a.y;
                xv[4 * q + 2] = a.z; xv[4 * q + 3] = a.w;
            }
        } else {
#pragma unroll
            for (int i = 0; i < 24; ++i) {
                const int g = g0 + i;
                xv[i] = ((unsigned)g < (unsigned)Tn) ? xrow[g] : 0.f;
            }
        }

        // out(t = tb+jj) = sum_k w[k][tb+jj] * x[t+k-7] = xv[jj+k+1]
        float o8[8] = {0.f, 0.f, 0.f, 0.f, 0.f, 0.f, 0.f, 0.f};
#pragma unroll
        for (int k = 0; k < 15; ++k) {
#pragma unroll
            for (int jj = 0; jj < 8; ++jj) {
                const unsigned int u =
                    ((unsigned int)(unsigned short)wk[k][jj]) << 16;
                o8[jj] += __uint_as_float(u) * xv[jj + k + 1];
            }
        }

        f32x4 o0 = {o8[0], o8[1], o8[2], o8[3]};
        f32x4 o1 = {o8[4], o8[5], o8[6], o8[7]};
        float* dst = ob + (size_t)c * Tn + tb;
        __builtin_nontemporal_store(o0, reinterpret_cast<f32x4*>(dst));
        __builtin_nontemporal_store(o1, reinterpret_cast<f32x4*>(dst + 4));
    }
}

// ---------------------------------------------------------------------------
// kernel_launch — scratch plan:
//   d_ws  : w (B,H,K,T) BF16 = 15 MiB
//   d_out : [0,512K) W' bf16 (consumed by fused_weights before apply
//           overwrites d_out; stream-ordered)
// ---------------------------------------------------------------------------
extern "C" void kernel_launch(void* const* d_in, const int* in_sizes, int n_in,
                              void* d_out, int out_size, void* d_ws, size_t ws_size,
                              hipStream_t stream)
{
    const float* x = (const float*)d_in[0];
    const float* W = (const float*)d_in[1];
    float* out     = (float*)d_out;
    unsigned short* wks = (unsigned short*)d_ws;   // bf16 w workspace

    unsigned short* Wp = (unsigned short*)d_out;   // 512 KiB scratch in d_out

    lwc_wpad<<<dim3(Fp * Cn / 4 / 256), 256, 0, stream>>>(W, Wp);

    dim3 gF(Tn / 64, Bn);              // (64, 8) — unswizzled (A/B vs r10)
    lwc_fused_weights<<<gF, 256, 0, stream>>>(x, Wp, wks);

    lwc_apply<<<dim3(2048), 256, 0, stream>>>(x, wks, out);
}